// Round 4
// baseline (1521.001 us; speedup 1.0000x reference)
//
#include <hip/hip_runtime.h>
#include <hip/hip_bf16.h>

typedef float f32x4 __attribute__((ext_vector_type(4)));
typedef __bf16 bf16x8 __attribute__((ext_vector_type(8)));
typedef unsigned short u16x8 __attribute__((ext_vector_type(8)));
typedef unsigned short u16;

__device__ __forceinline__ u16 f2bf(float f) {
  unsigned int u = __float_as_uint(f);
  u += 0x7FFFu + ((u >> 16) & 1u);          // RNE
  return (u16)(u >> 16);
}
__device__ __forceinline__ float bf2f(u16 s) {
  return __uint_as_float(((unsigned int)s) << 16);
}
__device__ __forceinline__ float gelu_f(float x) {
  return 0.5f * x * (1.0f + erff(x * 0.70710678118654752f)); // erf GELU
}
__device__ __forceinline__ void gload_lds16(const void* g, void* l) {
  __builtin_amdgcn_global_load_lds((const __attribute__((address_space(1))) void*)g,
                                   (__attribute__((address_space(3))) void*)l, 16, 0, 0);
}

// ---------------- merged weight conversion ----------------
__global__ void cvt_all(const float* __restrict__ e1, const float* __restrict__ e2,
                        const float* __restrict__ e3, const float* __restrict__ d1,
                        const float* __restrict__ d2, const float* __restrict__ d3,
                        const float* __restrict__ mx, u16* __restrict__ dst)
{
  int i = blockIdx.x * blockDim.x + threadIdx.x;
  int stride = gridDim.x * blockDim.x;
  for (; i < 3145728; i += stride) {
    float v;
    if (i < 524288)        v = e1[i];
    else if (i < 786432)   v = e2[i - 524288];
    else if (i < 1048576)  v = e3[i - 786432];
    else if (i < 1310720)  v = d1[i - 1048576];
    else if (i < 1572864)  v = d2[i - 1310720];
    else if (i < 2097152)  v = d3[i - 1572864];
    else {
      // mix_w [L,16,16,32,32] (l,bi,j,e,d) -> W[l][o=bi*32+e][k=j*32+d]
      int j = i - 2097152;
      int l = j >> 18, rem = j & 262143;
      int o = rem >> 9, k = rem & 511;
      int bi = o >> 5, e = o & 31, jj = k >> 5, dd = k & 31;
      v = mx[(((l * 16 + bi) * 16 + jj) * 32 + e) * 32 + dd];
    }
    dst[i] = f2bf(v);
  }
}

// ---------------- GEMM: C = A * W^T (+epilogue), 2-phase dbuf pipeline ----------------
// EPI: 0 = bias+GELU -> bf16 ; 1 = bias -> bf16 ; 2 = latent combine -> bf16 ; 3 = bias -> f32
// BM=BN=128, BK=64, 256 threads (4 waves as 2x2), dbuf LDS 64KB -> 2 blocks/CU.
// Per K-step: issue next-tile staging FIRST, compute current, ONE barrier (T3-minimum).
template<int EPI, bool AF32>
__global__ __launch_bounds__(256, 2)
void gemm_bt(const void* __restrict__ Ap, const u16* __restrict__ Bw,
             const float* __restrict__ bias, void* __restrict__ Cp,
             const u16* __restrict__ zOld, const float* __restrict__ scales,
             const float* __restrict__ gateBias, int M, int N, int K)
{
  constexpr int BK = 64;
  __shared__ u16 At[2][128 * BK];
  __shared__ u16 Bt[2][128 * BK];
  const int tid = threadIdx.x;
  const int lane = tid & 63;
  const int wid = tid >> 6;

  // XCD-aware bijective swizzle (ny % 8 == 0 for all our shapes)
  const int nx = N >> 7;
  const int ny = M >> 7;
  const int d = blockIdx.x;
  const int xcd = d & 7;
  const int seq = d >> 3;
  const int by = xcd * (ny >> 3) + seq / nx;
  const int bx = seq - (seq / nx) * nx;
  const int m0 = by << 7;
  const int n0 = bx << 7;

  const int wr = wid >> 1, wc = wid & 1;   // 2x2 wave grid, wave tile 64x64
  const int r16 = lane & 15;
  const int kg = (lane >> 4) << 3;         // k sub-offset 0,8,16,24
  const int sw = (r16 & 7) << 4;           // XOR swizzle for ds_read rows

  const int NT = K >> 6;
  f32x4 acc[4][4] = {};
  float4 aA[8];                            // AF32 staging regs (T14 split)

  const float* Af = (const float*)Ap;
  const u16*   Ab = (const u16*)Ap;

  // ---- prologue: stage tile 0 into buf 0 ----
  if constexpr (AF32) {
    #pragma unroll
    for (int it = 0; it < 4; ++it) {
      int c = it * 256 + tid;              // 16B-dst chunk id (1024 total)
      int row = c >> 3;
      int cb = (c & 7) << 4;
      const float* src = Af + (size_t)(m0 + row) * K + ((c & 7) << 3);
      float4 v0 = *(const float4*)src;
      float4 v1 = *(const float4*)(src + 4);
      u16x8 u;
      u[0] = f2bf(v0.x); u[1] = f2bf(v0.y); u[2] = f2bf(v0.z); u[3] = f2bf(v0.w);
      u[4] = f2bf(v1.x); u[5] = f2bf(v1.y); u[6] = f2bf(v1.z); u[7] = f2bf(v1.w);
      *(u16x8*)((char*)At[0] + row * 128 + (cb ^ ((row & 7) << 4))) = u;
    }
  } else {
    #pragma unroll
    for (int it = 0; it < 4; ++it) {
      int c = ((it * 4 + wid) << 6) + lane;
      int row = c >> 3;
      int cb = (c & 7) << 4;
      const char* g = (const char*)(Ab + (size_t)(m0 + row) * K) + (cb ^ ((row & 7) << 4));
      gload_lds16(g, (char*)At[0] + ((it * 4 + wid) << 10));
    }
  }
  #pragma unroll
  for (int it = 0; it < 4; ++it) {
    int c = ((it * 4 + wid) << 6) + lane;
    int row = c >> 3;
    int cb = (c & 7) << 4;
    const char* g = (const char*)(Bw + (size_t)(n0 + row) * K) + (cb ^ ((row & 7) << 4));
    gload_lds16(g, (char*)Bt[0] + ((it * 4 + wid) << 10));
  }
  __syncthreads();

  // ---- main loop: one barrier per K-step, prefetch issued before compute ----
  for (int kt = 0; kt < NT; ++kt) {
    const int cur = kt & 1;
    const bool hasNext = (kt + 1) < NT;

    // (1) issue next-tile staging (no waits here)
    if (hasNext) {
      const int kn = (kt + 1) << 6;
      if constexpr (AF32) {
        #pragma unroll
        for (int it = 0; it < 4; ++it) {
          int c = it * 256 + tid;
          int row = c >> 3;
          const float* src = Af + (size_t)(m0 + row) * K + kn + ((c & 7) << 3);
          aA[it * 2]     = *(const float4*)src;
          aA[it * 2 + 1] = *(const float4*)(src + 4);
        }
      } else {
        #pragma unroll
        for (int it = 0; it < 4; ++it) {
          int c = ((it * 4 + wid) << 6) + lane;
          int row = c >> 3;
          int cb = (c & 7) << 4;
          const char* g = (const char*)(Ab + (size_t)(m0 + row) * K + kn) + (cb ^ ((row & 7) << 4));
          gload_lds16(g, (char*)At[cur ^ 1] + ((it * 4 + wid) << 10));
        }
      }
      #pragma unroll
      for (int it = 0; it < 4; ++it) {
        int c = ((it * 4 + wid) << 6) + lane;
        int row = c >> 3;
        int cb = (c & 7) << 4;
        const char* g = (const char*)(Bw + (size_t)(n0 + row) * K + kn) + (cb ^ ((row & 7) << 4));
        gload_lds16(g, (char*)Bt[cur ^ 1] + ((it * 4 + wid) << 10));
      }
    }

    // (2) compute current tile
    #pragma unroll
    for (int kk = 0; kk < BK; kk += 32) {
      bf16x8 av[4], bv[4];
      #pragma unroll
      for (int m = 0; m < 4; ++m) {
        int row = wr * 64 + m * 16 + r16;
        av[m] = *(const bf16x8*)((const char*)At[cur] + row * 128 + ((((kk + kg) << 1)) ^ sw));
      }
      #pragma unroll
      for (int n = 0; n < 4; ++n) {
        int row = wc * 64 + n * 16 + r16;
        bv[n] = *(const bf16x8*)((const char*)Bt[cur] + row * 128 + ((((kk + kg) << 1)) ^ sw));
      }
      #pragma unroll
      for (int m = 0; m < 4; ++m)
        #pragma unroll
        for (int n = 0; n < 4; ++n)
          acc[m][n] = __builtin_amdgcn_mfma_f32_16x16x32_bf16(av[m], bv[n], acc[m][n], 0, 0, 0);
    }

    // (3) AF32: land staged regs into next LDS buffer (after compute, before barrier)
    if (hasNext) {
      if constexpr (AF32) {
        #pragma unroll
        for (int it = 0; it < 4; ++it) {
          int c = it * 256 + tid;
          int row = c >> 3;
          int cb = (c & 7) << 4;
          float4 v0 = aA[it * 2], v1 = aA[it * 2 + 1];
          u16x8 u;
          u[0] = f2bf(v0.x); u[1] = f2bf(v0.y); u[2] = f2bf(v0.z); u[3] = f2bf(v0.w);
          u[4] = f2bf(v1.x); u[5] = f2bf(v1.y); u[6] = f2bf(v1.z); u[7] = f2bf(v1.w);
          *(u16x8*)((char*)At[cur ^ 1] + row * 128 + (cb ^ ((row & 7) << 4))) = u;
        }
      }
    }
    __syncthreads();   // single barrier per K-step (drains vmcnt for gload_lds)
  }

  // ---- epilogue ----  D layout: col = lane&15, row = (lane>>4)*4 + reg
  const int colBase = n0 + wc * 64 + r16;
  const int rowBase = m0 + wr * 64 + ((lane >> 4) << 2);
  #pragma unroll
  for (int n = 0; n < 4; ++n) {
    int col = colBase + n * 16;
    float bv_ = 0.f, gate = 0.f;
    if constexpr (EPI == 0 || EPI == 1 || EPI == 3) bv_ = bias[col];
    if constexpr (EPI == 2) gate = 1.f / (1.f + expf(-gateBias[col >> 5]));
    #pragma unroll
    for (int m = 0; m < 4; ++m) {
      #pragma unroll
      for (int r = 0; r < 4; ++r) {
        int row = rowBase + m * 16 + r;
        float v = acc[m][n][r];
        if constexpr (EPI == 0) {
          ((u16*)Cp)[(size_t)row * N + col] = f2bf(gelu_f(v + bv_));
        } else if constexpr (EPI == 1) {
          ((u16*)Cp)[(size_t)row * N + col] = f2bf(v + bv_);
        } else if constexpr (EPI == 2) {
          float sc = scales[(size_t)row * 16 + (col >> 5)];
          float zo = bf2f(zOld[(size_t)row * 512 + col]);
          ((u16*)Cp)[(size_t)row * N + col] = f2bf(zo * (1.f + sc) + gate * v);
        } else {
          ((float*)Cp)[(size_t)row * N + col] = v + bv_;
        }
      }
    }
  }
}

// ---------------- per-row bundle-norm MLP -> scales ----------------
__global__ __launch_bounds__(256)
void norm_mlp(const u16* __restrict__ z,
              const float* __restrict__ w1, const float* __restrict__ b1,
              const float* __restrict__ w2, const float* __restrict__ b2,
              const float* __restrict__ w3, float* __restrict__ scales, int Mrows)
{
  const int lane = threadIdx.x & 63;
  const int wv = threadIdx.x >> 6;
  for (int row = blockIdx.x * 4 + wv; row < Mrows; row += gridDim.x * 4) {
    u16x8 zv = *(const u16x8*)(z + (size_t)row * 512 + lane * 8);
    float ss = 0.f;
    #pragma unroll
    for (int j = 0; j < 8; ++j) { float f = bf2f(zv[j]); ss += f * f; }
    ss += __shfl_xor(ss, 1);
    ss += __shfl_xor(ss, 2);                 // 4-lane group = one 32-elem bundle
    float nrm = sqrtf(ss) + 1e-8f;
    float h1 = b1[lane];
    #pragma unroll
    for (int i = 0; i < 16; ++i) h1 += __shfl(nrm, i * 4) * w1[lane * 16 + i];
    h1 = gelu_f(h1);
    float h2 = b2[lane];
    #pragma unroll
    for (int k = 0; k < 64; ++k) h2 += __shfl(h1, k) * w2[lane * 64 + k];
    h2 = gelu_f(h2);
    float s = 0.f;
    const int i16 = lane & 15;
    #pragma unroll
    for (int k = 0; k < 64; ++k) s += __shfl(h2, k) * w3[i16 * 64 + k];
    if (lane < 16) {
      s = (s > 20.f) ? s : log1pf(expf(s));  // softplus
      scales[(size_t)row * 16 + lane] = s;
    }
  }
}

// ---------------- launch ----------------
extern "C" void kernel_launch(void* const* d_in, const int* in_sizes, int n_in,
                              void* d_out, int out_size, void* d_ws, size_t ws_size,
                              hipStream_t stream)
{
  (void)in_sizes; (void)n_in; (void)out_size; (void)ws_size;
  const float* x      = (const float*)d_in[0];
  const float* enc_w1 = (const float*)d_in[1];
  const float* enc_b1 = (const float*)d_in[2];
  const float* enc_w2 = (const float*)d_in[3];
  const float* enc_b2 = (const float*)d_in[4];
  const float* enc_w3 = (const float*)d_in[5];
  const float* enc_b3 = (const float*)d_in[6];
  const float* mlp1_w = (const float*)d_in[7];
  const float* mlp1_b = (const float*)d_in[8];
  const float* mlp2_w = (const float*)d_in[9];
  const float* mlp2_b = (const float*)d_in[10];
  const float* mlp3_w = (const float*)d_in[11];
  const float* mix_w  = (const float*)d_in[12];
  const float* gate_b = (const float*)d_in[13];
  const float* dec_w1 = (const float*)d_in[14];
  const float* dec_b1 = (const float*)d_in[15];
  const float* dec_w2 = (const float*)d_in[16];
  const float* dec_b2 = (const float*)d_in[17];
  const float* dec_w3 = (const float*)d_in[18];
  const float* dec_b3 = (const float*)d_in[19];

  char* ws = (char*)d_ws;
  u16*   zA     = (u16*)ws;                            // 64 MB
  u16*   zB     = (u16*)(ws + (size_t)(64u << 20));    // 64 MB
  float* scales = (float*)(ws + (size_t)(128u << 20)); // 4 MB
  u16*   wBase  = (u16*)(ws + (size_t)(132u << 20));
  u16*   wE1    = wBase;
  u16*   wE2    = wE1 + 524288;
  u16*   wE3    = wE2 + 262144;
  u16*   wD1    = wE3 + 262144;
  u16*   wD2    = wD1 + 262144;
  u16*   wD3    = wD2 + 262144;
  u16*   wMix   = wD3 + 524288;                        // 4 x 512 x 512

  cvt_all<<<512, 256, 0, stream>>>(enc_w1, enc_w2, enc_w3, dec_w1, dec_w2, dec_w3,
                                   mix_w, wBase);

  const int M = 65536;
  dim3 blk(256);
  const int g512  = 4 * 512;   // (N/128) * (M/128), 1-D swizzled
  const int g1024 = 8 * 512;

  // encoder
  gemm_bt<0, true ><<<g512, blk, 0, stream>>>(x,  wE1, enc_b1, zA, nullptr, nullptr, nullptr, M, 512, 1024);
  gemm_bt<0, false><<<g512, blk, 0, stream>>>(zA, wE2, enc_b2, zB, nullptr, nullptr, nullptr, M, 512, 512);
  gemm_bt<1, false><<<g512, blk, 0, stream>>>(zB, wE3, enc_b3, zA, nullptr, nullptr, nullptr, M, 512, 512);

  // latent layers
  u16* cur = zA;
  u16* nxt = zB;
  for (int l = 0; l < 4; ++l) {
    norm_mlp<<<2048, dim3(256), 0, stream>>>(cur, mlp1_w + l * 1024, mlp1_b + l * 64,
                                             mlp2_w + l * 4096, mlp2_b + l * 64,
                                             mlp3_w + l * 1024, scales, M);
    gemm_bt<2, false><<<g512, blk, 0, stream>>>(cur, wMix + (size_t)l * 262144, nullptr, nxt,
                                                cur, scales, gate_b + l * 16, M, 512, 512);
    u16* t = cur; cur = nxt; nxt = t;
  }

  // decoder
  gemm_bt<0, false><<<g512, blk, 0, stream>>>(cur, wD1, dec_b1, nxt, nullptr, nullptr, nullptr, M, 512, 512);
  { u16* t = cur; cur = nxt; nxt = t; }
  gemm_bt<0, false><<<g512, blk, 0, stream>>>(cur, wD2, dec_b2, nxt, nullptr, nullptr, nullptr, M, 512, 512);
  { u16* t = cur; cur = nxt; nxt = t; }
  gemm_bt<3, false><<<g1024, blk, 0, stream>>>(cur, wD3, dec_b3, d_out, nullptr, nullptr, nullptr, M, 1024, 512);
}

// Round 5
// 1472.550 us; speedup vs baseline: 1.0329x; 1.0329x over previous
//
#include <hip/hip_runtime.h>
#include <hip/hip_bf16.h>

typedef float f32x4 __attribute__((ext_vector_type(4)));
typedef __bf16 bf16x8 __attribute__((ext_vector_type(8)));
typedef unsigned short u16x8 __attribute__((ext_vector_type(8)));
typedef unsigned short u16;

// LDS map (dynamic, 155904 B total):
//   zA @ 0        (64 KB)  [64 rows][512 cols] bf16, XOR-swizzled
//   zB @ 65536    (64 KB)
//   nrm @ 131072  (4 KB)   [64][16] f32        (also enc1 x-stage @131072, 8KB)
//   h   @ 135168  (16640)  [64][65] f32 (padded stride vs bank conflicts)
//   scl @ 151808  (4 KB)   [64][16] f32
#define SMEM_BYTES 155904
#define ZA_OFF 0
#define ZB_OFF 65536
#define NRM_OFF 131072
#define H_OFF 135168
#define SCL_OFF 151808

__device__ __forceinline__ u16 f2bf(float f) {
  unsigned int u = __float_as_uint(f);
  u += 0x7FFFu + ((u >> 16) & 1u);          // RNE
  return (u16)(u >> 16);
}
__device__ __forceinline__ float bf2f(u16 s) {
  return __uint_as_float(((unsigned int)s) << 16);
}
__device__ __forceinline__ float gelu_f(float x) {
  return 0.5f * x * (1.0f + erff(x * 0.70710678118654752f)); // erf GELU
}
__device__ __forceinline__ bf16x8 ldg_bf16x8(const u16* p) {
  return *(const bf16x8*)p;
}

// ---------------- merged weight conversion (unchanged, verified) ----------------
__global__ void cvt_all(const float* __restrict__ e1, const float* __restrict__ e2,
                        const float* __restrict__ e3, const float* __restrict__ d1,
                        const float* __restrict__ d2, const float* __restrict__ d3,
                        const float* __restrict__ mx, u16* __restrict__ dst)
{
  int i = blockIdx.x * blockDim.x + threadIdx.x;
  int stride = gridDim.x * blockDim.x;
  for (; i < 3145728; i += stride) {
    float v;
    if (i < 524288)        v = e1[i];
    else if (i < 786432)   v = e2[i - 524288];
    else if (i < 1048576)  v = e3[i - 786432];
    else if (i < 1310720)  v = d1[i - 1048576];
    else if (i < 1572864)  v = d2[i - 1310720];
    else if (i < 2097152)  v = d3[i - 1572864];
    else {
      // mix_w [L,16,16,32,32] (l,bi,j,e,d) -> W[l][o=bi*32+e][k=j*32+d]
      int j = i - 2097152;
      int l = j >> 18, rem = j & 262143;
      int o = rem >> 9, k = rem & 511;
      int bi = o >> 5, e = o & 31, jj = k >> 5, dd = k & 31;
      v = mx[(((l * 16 + bi) * 16 + jj) * 32 + e) * 32 + dd];
    }
    dst[i] = f2bf(v);
  }
}

// ---------------- fused-network building blocks ----------------
// GEMM over the LDS-resident strip: out[64 x 512(+nOff)] = z[64 x 512] * W^T
// 8 waves, wave wid owns cols [wid*64, wid*64+64). A from LDS (XOR swizzle),
// B direct global->VGPR (L2-resident weights). EPI: 0 gelu+bias->LDS,
// 1 bias->LDS, 2 latent-combine->LDS, 3 bias->f32 global.
template<int EPI>
__device__ __forceinline__ void gemm512(char* __restrict__ smem, int inOff, int outOff,
    const u16* __restrict__ W, const float* __restrict__ bias,
    const float* __restrict__ gateBias, float* __restrict__ outG, int nOff, int m0)
{
  __syncthreads();                         // previous phase's LDS writes visible
  const int tid = threadIdx.x;
  const int lane = tid & 63;
  const int wid = tid >> 6;
  const int c0 = wid << 6;
  const int r16 = lane & 15;
  const int kg = (lane >> 4) << 3;
  const int sw = (r16 & 7) << 4;
  const char* zin = smem + inOff;

  f32x4 acc[4][4] = {};
  #pragma unroll 4
  for (int ks = 0; ks < 16; ++ks) {
    const int kk = ks << 5;
    bf16x8 av[4], bv[4];
    #pragma unroll
    for (int nt = 0; nt < 4; ++nt)
      bv[nt] = ldg_bf16x8(W + (size_t)(nOff + c0 + nt * 16 + r16) * 512 + kk + kg);
    #pragma unroll
    for (int mt = 0; mt < 4; ++mt)
      av[mt] = *(const bf16x8*)(zin + (mt * 16 + r16) * 1024 + (((kk + kg) << 1) ^ sw));
    #pragma unroll
    for (int mt = 0; mt < 4; ++mt)
      #pragma unroll
      for (int nt = 0; nt < 4; ++nt)
        acc[mt][nt] = __builtin_amdgcn_mfma_f32_16x16x32_bf16(av[mt], bv[nt], acc[mt][nt], 0, 0, 0);
  }

  // epilogue; D layout: col = lane&15, row = (lane>>4)*4 + reg (verified)
  const float* scl = (const float*)(smem + SCL_OFF);
  char* zout = smem + outOff;
  #pragma unroll
  for (int nt = 0; nt < 4; ++nt) {
    const int col = c0 + nt * 16 + r16;    // 0..511 layer-local
    float bv_ = 0.f, gate = 0.f;
    if constexpr (EPI == 0 || EPI == 1 || EPI == 3) bv_ = bias[nOff + col];
    if constexpr (EPI == 2) gate = 1.f / (1.f + expf(-gateBias[col >> 5]));
    #pragma unroll
    for (int mt = 0; mt < 4; ++mt) {
      #pragma unroll
      for (int r = 0; r < 4; ++r) {
        const int row = mt * 16 + ((lane >> 4) << 2) + r;
        const int zb = row * 1024 + ((col << 1) ^ ((row & 7) << 4));
        float v = acc[mt][nt][r];
        if constexpr (EPI == 0) {
          *(u16*)(zout + zb) = f2bf(gelu_f(v + bv_));
        } else if constexpr (EPI == 1) {
          *(u16*)(zout + zb) = f2bf(v + bv_);
        } else if constexpr (EPI == 2) {
          float sc = scl[row * 16 + (col >> 5)];
          float zo = bf2f(*(const u16*)(zin + zb));
          *(u16*)(zout + zb) = f2bf(zo * (1.f + sc) + gate * v);
        } else {
          outG[(size_t)(m0 + row) * 1024 + nOff + col] = v + bv_;
        }
      }
    }
  }
}

// bundle norms -> 16->64->64->16 MLP -> softplus scales (all in LDS scratch)
__device__ __forceinline__ void norm_phase(char* __restrict__ smem, int zOff,
    const float* __restrict__ w1, const float* __restrict__ b1,
    const float* __restrict__ w2, const float* __restrict__ b2,
    const float* __restrict__ w3)
{
  __syncthreads();
  const int tid = threadIdx.x;
  float* nrm = (float*)(smem + NRM_OFF);
  float* h   = (float*)(smem + H_OFF);     // [64][65] f32
  float* scl = (float*)(smem + SCL_OFF);
  const char* z = smem + zOff;

  // N1: norms[r][b] over 32-elem bundles
  #pragma unroll
  for (int p = 0; p < 2; ++p) {
    int task = tid + p * 512;
    int r = task >> 4, b = task & 15;
    float ss = 0.f;
    #pragma unroll
    for (int s = 0; s < 4; ++s) {
      u16x8 v = *(const u16x8*)(z + r * 1024 + ((b * 64 + s * 16) ^ ((r & 7) << 4)));
      #pragma unroll
      for (int j = 0; j < 8; ++j) { float f = bf2f(v[j]); ss += f * f; }
    }
    nrm[r * 16 + b] = sqrtf(ss) + 1e-8f;
  }
  __syncthreads();

  const int j = tid & 63;
  const int r0w = tid >> 6;                // wave id = row base (broadcast LDS reads)
  // N2: h1 = gelu(nrm @ w1^T + b1)
  {
    float a[8];
    #pragma unroll
    for (int p = 0; p < 8; ++p) a[p] = b1[j];
    #pragma unroll
    for (int i = 0; i < 16; ++i) {
      float wv = w1[j * 16 + i];
      #pragma unroll
      for (int p = 0; p < 8; ++p) a[p] += nrm[(r0w + 8 * p) * 16 + i] * wv;
    }
    #pragma unroll
    for (int p = 0; p < 8; ++p) h[(r0w + 8 * p) * 65 + j] = gelu_f(a[p]);
  }
  __syncthreads();
  // N3: h2 = gelu(h1 @ w2^T + b2), computed to regs then overwrite h
  {
    float a[8];
    #pragma unroll
    for (int p = 0; p < 8; ++p) a[p] = b2[j];
    for (int k = 0; k < 64; ++k) {
      float wv = w2[j * 64 + k];
      #pragma unroll
      for (int p = 0; p < 8; ++p) a[p] += h[(r0w + 8 * p) * 65 + k] * wv;
    }
    __syncthreads();
    #pragma unroll
    for (int p = 0; p < 8; ++p) h[(r0w + 8 * p) * 65 + j] = gelu_f(a[p]);
  }
  __syncthreads();
  // N4: scales = softplus(h2 @ w3^T)
  {
    const int b = tid & 15;
    const int r0 = tid >> 4;               // 0..31
    float a0 = 0.f, a1 = 0.f;
    for (int k = 0; k < 64; ++k) {
      float wv = w3[b * 64 + k];
      a0 += h[r0 * 65 + k] * wv;
      a1 += h[(r0 + 32) * 65 + k] * wv;
    }
    a0 = (a0 > 20.f) ? a0 : log1pf(expf(a0));
    a1 = (a1 > 20.f) ? a1 : log1pf(expf(a1));
    scl[r0 * 16 + b] = a0;
    scl[(r0 + 32) * 16 + b] = a1;
  }
  __syncthreads();
}

// ---------------- the fused network kernel ----------------
__global__ __launch_bounds__(512, 2)
void ugn_mega(const float* __restrict__ x,
              const float* __restrict__ enc_b1, const float* __restrict__ enc_b2,
              const float* __restrict__ enc_b3,
              const float* __restrict__ mlp1_w, const float* __restrict__ mlp1_b,
              const float* __restrict__ mlp2_w, const float* __restrict__ mlp2_b,
              const float* __restrict__ mlp3_w, const float* __restrict__ gate_b,
              const float* __restrict__ dec_b1, const float* __restrict__ dec_b2,
              const float* __restrict__ dec_b3,
              const u16* __restrict__ wE1, const u16* __restrict__ wE2,
              const u16* __restrict__ wE3, const u16* __restrict__ wMix,
              const u16* __restrict__ wD1, const u16* __restrict__ wD2,
              const u16* __restrict__ wD3, float* __restrict__ out)
{
  extern __shared__ char smem[];
  const int m0 = blockIdx.x << 6;          // 64-row strip
  const int tid = threadIdx.x;
  const int lane = tid & 63;
  const int wid = tid >> 6;
  const int c0 = wid << 6;
  const int r16 = lane & 15;
  const int kg = (lane >> 4) << 3;
  const int swz = (r16 & 7) << 4;

  // ===== enc1: z = gelu(x @ wE1^T + b1), K=1024, x f32 streamed in 64-k chunks =====
  {
    char* stage = smem + NRM_OFF;          // 8 KB [64][64] bf16 XOR (scratch unused now)
    const float* xs = x + (size_t)m0 * 1024;
    const int xr = tid >> 3;               // row 0..63
    const int kp = (tid & 7) << 3;         // k 0..56 step 8
    float4 v0 = *(const float4*)(xs + (size_t)xr * 1024 + kp);
    float4 v1 = *(const float4*)(xs + (size_t)xr * 1024 + kp + 4);
    f32x4 acc[4][4] = {};
    for (int c = 0; c < 16; ++c) {
      u16x8 u;
      u[0] = f2bf(v0.x); u[1] = f2bf(v0.y); u[2] = f2bf(v0.z); u[3] = f2bf(v0.w);
      u[4] = f2bf(v1.x); u[5] = f2bf(v1.y); u[6] = f2bf(v1.z); u[7] = f2bf(v1.w);
      *(u16x8*)(stage + xr * 128 + ((kp << 1) ^ ((xr & 7) << 4))) = u;
      __syncthreads();
      if (c < 15) {                        // T14: issue next chunk's loads early
        const float* src = xs + (size_t)xr * 1024 + (c + 1) * 64 + kp;
        v0 = *(const float4*)src;
        v1 = *(const float4*)(src + 4);
      }
      #pragma unroll
      for (int ks = 0; ks < 2; ++ks) {
        const int kk = ks << 5;
        bf16x8 av[4], bv[4];
        #pragma unroll
        for (int nt = 0; nt < 4; ++nt)
          bv[nt] = ldg_bf16x8(wE1 + (size_t)(c0 + nt * 16 + r16) * 1024 + c * 64 + kk + kg);
        #pragma unroll
        for (int mt = 0; mt < 4; ++mt)
          av[mt] = *(const bf16x8*)(stage + (mt * 16 + r16) * 128 + (((kk + kg) << 1) ^ swz));
        #pragma unroll
        for (int mt = 0; mt < 4; ++mt)
          #pragma unroll
          for (int nt = 0; nt < 4; ++nt)
            acc[mt][nt] = __builtin_amdgcn_mfma_f32_16x16x32_bf16(av[mt], bv[nt], acc[mt][nt], 0, 0, 0);
      }
      __syncthreads();
    }
    // epilogue -> zA (gelu+bias)
    char* zout = smem + ZA_OFF;
    #pragma unroll
    for (int nt = 0; nt < 4; ++nt) {
      const int col = c0 + nt * 16 + r16;
      const float bb = enc_b1[col];
      #pragma unroll
      for (int mt = 0; mt < 4; ++mt) {
        #pragma unroll
        for (int r = 0; r < 4; ++r) {
          const int row = mt * 16 + ((lane >> 4) << 2) + r;
          *(u16*)(zout + row * 1024 + ((col << 1) ^ ((row & 7) << 4))) =
              f2bf(gelu_f(acc[mt][nt][r] + bb));
        }
      }
    }
  }

  // ===== enc2 / enc3 =====
  gemm512<0>(smem, ZA_OFF, ZB_OFF, wE2, enc_b2, nullptr, nullptr, 0, m0);
  gemm512<1>(smem, ZB_OFF, ZA_OFF, wE3, enc_b3, nullptr, nullptr, 0, m0);

  // ===== 4 latent layers (alternate zA/zB; ends back in zA) =====
  #pragma unroll
  for (int l = 0; l < 4; ++l) {
    const int zi = (l & 1) ? ZB_OFF : ZA_OFF;
    const int zo = (l & 1) ? ZA_OFF : ZB_OFF;
    norm_phase(smem, zi, mlp1_w + l * 1024, mlp1_b + l * 64,
               mlp2_w + l * 4096, mlp2_b + l * 64, mlp3_w + l * 1024);
    gemm512<2>(smem, zi, zo, wMix + (size_t)l * 262144, nullptr, gate_b + l * 16,
               nullptr, 0, m0);
  }

  // ===== decoder =====
  gemm512<0>(smem, ZA_OFF, ZB_OFF, wD1, dec_b1, nullptr, nullptr, 0, m0);
  gemm512<0>(smem, ZB_OFF, ZA_OFF, wD2, dec_b2, nullptr, nullptr, 0, m0);
  gemm512<3>(smem, ZA_OFF, ZB_OFF, wD3, dec_b3, nullptr, out, 0, m0);
  gemm512<3>(smem, ZA_OFF, ZB_OFF, wD3, dec_b3, nullptr, out, 512, m0);
}

// ---------------- launch ----------------
extern "C" void kernel_launch(void* const* d_in, const int* in_sizes, int n_in,
                              void* d_out, int out_size, void* d_ws, size_t ws_size,
                              hipStream_t stream)
{
  (void)in_sizes; (void)n_in; (void)out_size; (void)ws_size;
  const float* x      = (const float*)d_in[0];
  const float* enc_w1 = (const float*)d_in[1];
  const float* enc_b1 = (const float*)d_in[2];
  const float* enc_w2 = (const float*)d_in[3];
  const float* enc_b2 = (const float*)d_in[4];
  const float* enc_w3 = (const float*)d_in[5];
  const float* enc_b3 = (const float*)d_in[6];
  const float* mlp1_w = (const float*)d_in[7];
  const float* mlp1_b = (const float*)d_in[8];
  const float* mlp2_w = (const float*)d_in[9];
  const float* mlp2_b = (const float*)d_in[10];
  const float* mlp3_w = (const float*)d_in[11];
  const float* mix_w  = (const float*)d_in[12];
  const float* gate_b = (const float*)d_in[13];
  const float* dec_w1 = (const float*)d_in[14];
  const float* dec_b1 = (const float*)d_in[15];
  const float* dec_w2 = (const float*)d_in[16];
  const float* dec_b2 = (const float*)d_in[17];
  const float* dec_w3 = (const float*)d_in[18];
  const float* dec_b3 = (const float*)d_in[19];

  u16* wBase = (u16*)d_ws;
  u16* wE1 = wBase;
  u16* wE2 = wE1 + 524288;
  u16* wE3 = wE2 + 262144;
  u16* wD1 = wE3 + 262144;
  u16* wD2 = wD1 + 262144;
  u16* wD3 = wD2 + 262144;
  u16* wMix = wD3 + 524288;

  cvt_all<<<512, 256, 0, stream>>>(enc_w1, enc_w2, enc_w3, dec_w1, dec_w2, dec_w3,
                                   mix_w, wBase);

  static int smemSet = 0;
  if (!smemSet) {
    hipFuncSetAttribute(reinterpret_cast<const void*>(&ugn_mega),
                        hipFuncAttributeMaxDynamicSharedMemorySize, SMEM_BYTES);
    smemSet = 1;
  }

  ugn_mega<<<1024, 512, SMEM_BYTES, stream>>>(
      x, enc_b1, enc_b2, enc_b3, mlp1_w, mlp1_b, mlp2_w, mlp2_b, mlp3_w, gate_b,
      dec_b1, dec_b2, dec_b3, wE1, wE2, wE3, wMix, wD1, wD2, wD3, (float*)d_out);
}